// Round 2
// baseline (964.465 us; speedup 1.0000x reference)
//
#include <hip/hip_runtime.h>

typedef __attribute__((ext_vector_type(8))) short bf16x8;
typedef __attribute__((ext_vector_type(4))) float f32x4;

__device__ __forceinline__ float bf2f(short s) {
    union { unsigned int i; float f; } v;
    v.i = ((unsigned int)(unsigned short)s) << 16;
    return v.f;
}
__device__ __forceinline__ short f2bf(float f) {
    unsigned int x = __float_as_uint(f);
    unsigned int r = (x + 0x7fffu + ((x >> 16) & 1u)) >> 16;
    return (short)r;
}

// ---------------------------------------------------------------------------
// Transpose f32 -> bf16 with zero-pad of output rows:
// in: R x C (row-major f32) -> out: Cout x R bf16, out[c][r] = (c<C)? in[r][c] : 0
// grid = (R/64, Cout/64), block = 256
// ---------------------------------------------------------------------------
__global__ __launch_bounds__(256) void transpose_cvt(
    const float* __restrict__ in, short* __restrict__ out,
    int R, int C, int Cout)
{
    __shared__ short tile[64][65];
    const int r0 = blockIdx.x << 6;
    const int c0 = blockIdx.y << 6;
    const int t = threadIdx.x;
#pragma unroll
    for (int i = 0; i < 16; ++i) {
        int idx = t + (i << 8);
        int rr = idx >> 6, cc = idx & 63;
        int c = c0 + cc;
        tile[rr][cc] = (c < C) ? f2bf(in[(size_t)(r0 + rr) * C + c]) : (short)0;
    }
    __syncthreads();
#pragma unroll
    for (int i = 0; i < 16; ++i) {
        int idx = t + (i << 8);
        int cc = idx >> 6, rr = idx & 63;
        out[(size_t)(c0 + cc) * R + r0 + rr] = tile[rr][cc];
    }
}

// ---------------------------------------------------------------------------
// C[M,N] = act(A[M,K] @ Bt[N,K]^T + bias[N]), fp32 accumulate, bf16 out.
// Fragment-direct (LDS-free, barrier-free): MFMA A-fragment = row (lane&15),
// k = (lane>>4)*8+j  -- k-contiguous, loaded straight from row-major global.
// Tile 64x64, block = 256 (4 waves; wave w -> rows 16w..16w+15).
// grid = (M/64, N/64).
// ---------------------------------------------------------------------------
template<int A_F32>
__global__ __launch_bounds__(256) void gemm_bt(
    const void* __restrict__ Ap, int lda,
    const short* __restrict__ Bt, int ldb,
    const float* __restrict__ bias,      // may be null (f32)
    short* __restrict__ C, int ldc,
    int K, int relu)
{
    const int t = threadIdx.x;
    const int wave = t >> 6;
    const int lane = t & 63;
    const int ml = lane & 15;
    const int kq = (lane >> 4) << 3;
    const int m0 = blockIdx.x << 6;
    const int n0 = blockIdx.y << 6;

    const int arow = m0 + (wave << 4) + ml;
    const float* apf = (const float*)Ap + (size_t)arow * lda + kq;
    const short* aps = (const short*)Ap + (size_t)arow * lda + kq;
    const short* bp0 = Bt + (size_t)(n0 + ml) * ldb + kq;
    const short* bp1 = bp0 + (size_t)16 * ldb;
    const short* bp2 = bp0 + (size_t)32 * ldb;
    const short* bp3 = bp0 + (size_t)48 * ldb;

    f32x4 acc[4];
#pragma unroll
    for (int i = 0; i < 4; ++i) acc[i] = (f32x4){0.f, 0.f, 0.f, 0.f};

#pragma unroll 2
    for (int k0 = 0; k0 < K; k0 += 32) {
        bf16x8 a;
        if (A_F32) {
            float4 x0 = *(const float4*)(apf + k0);
            float4 x1 = *(const float4*)(apf + k0 + 4);
            a[0] = f2bf(x0.x); a[1] = f2bf(x0.y); a[2] = f2bf(x0.z); a[3] = f2bf(x0.w);
            a[4] = f2bf(x1.x); a[5] = f2bf(x1.y); a[6] = f2bf(x1.z); a[7] = f2bf(x1.w);
        } else {
            a = *(const bf16x8*)(aps + k0);
        }
        bf16x8 b0 = *(const bf16x8*)(bp0 + k0);
        bf16x8 b1 = *(const bf16x8*)(bp1 + k0);
        bf16x8 b2 = *(const bf16x8*)(bp2 + k0);
        bf16x8 b3 = *(const bf16x8*)(bp3 + k0);
        acc[0] = __builtin_amdgcn_mfma_f32_16x16x32_bf16(a, b0, acc[0], 0, 0, 0);
        acc[1] = __builtin_amdgcn_mfma_f32_16x16x32_bf16(a, b1, acc[1], 0, 0, 0);
        acc[2] = __builtin_amdgcn_mfma_f32_16x16x32_bf16(a, b2, acc[2], 0, 0, 0);
        acc[3] = __builtin_amdgcn_mfma_f32_16x16x32_bf16(a, b3, acc[3], 0, 0, 0);
    }

    // C/D layout: col = lane&15, row = (lane>>4)*4 + reg
    const int ql = lane >> 4;
#pragma unroll
    for (int reg = 0; reg < 4; ++reg) {
        int r = m0 + (wave << 4) + (ql << 2) + reg;
#pragma unroll
        for (int nb = 0; nb < 4; ++nb) {
            int c = n0 + (nb << 4) + ml;
            float v = acc[nb][reg];
            if (bias) v += bias[c];
            if (relu) v = fmaxf(v, 0.f);
            C[(size_t)r * ldc + c] = f2bf(v);
        }
    }
}

// ---------------------------------------------------------------------------
// Fused final stage, fragment-direct (LDS-free, barrier-free).
// Hm already includes +b_cat (folded in via gemm bias).
//   A'[r,k] = bf16( (Hm[p0[r],k] + Tm[p1[r],k]) * U[r,k] )   built per-lane in
//   exact MFMA fragment layout; acc = A' @ Wt^T (Wt = zero-padded w_ctx^T).
//   out[r,c] = acc + b_ctx[c] + freq[obj[p0]*151+obj[p1], c]   (c < 51, f32)
// grid = 512, block = 256 (wave w -> rows r0+16w .. r0+16w+15).
// ---------------------------------------------------------------------------
__global__ __launch_bounds__(256) void fused_rel(
    const float* __restrict__ U,        // 32768 x 4096 f32
    const short* __restrict__ Hm,       // 1280 x 4096 bf16 (incl. b_cat)
    const short* __restrict__ Tm,       // 1280 x 4096 bf16
    const short* __restrict__ Wt,       // 64 x 4096 bf16
    const float* __restrict__ bctx,     // 51 f32
    const float* __restrict__ freq,     // 22801 x 51 f32
    const int* __restrict__ obj_preds,  // 1280 int32
    const int* __restrict__ pair_idx,   // 32768 x 2 int32
    float* __restrict__ out)            // 32768 x 51 f32
{
    const int t = threadIdx.x;
    const int wave = t >> 6;
    const int lane = t & 63;
    const int ml = lane & 15;
    const int kq = (lane >> 4) << 3;
    const int r0 = blockIdx.x << 6;
    const int rm = r0 + (wave << 4) + ml;

    const int p0 = pair_idx[2 * rm];
    const int p1 = pair_idx[2 * rm + 1];

    const float* up  = U  + (size_t)rm * 4096 + kq;
    const short* hp  = Hm + (size_t)p0 * 4096 + kq;
    const short* tp  = Tm + (size_t)p1 * 4096 + kq;
    const short* wp0 = Wt + (size_t)ml * 4096 + kq;
    const short* wp1 = wp0 + 16 * 4096;
    const short* wp2 = wp0 + 32 * 4096;
    const short* wp3 = wp0 + 48 * 4096;

    f32x4 acc[4];
#pragma unroll
    for (int i = 0; i < 4; ++i) acc[i] = (f32x4){0.f, 0.f, 0.f, 0.f};

#pragma unroll 2
    for (int k0 = 0; k0 < 4096; k0 += 32) {
        float4 u0 = *(const float4*)(up + k0);
        float4 u1 = *(const float4*)(up + k0 + 4);
        bf16x8 h  = *(const bf16x8*)(hp + k0);
        bf16x8 tv = *(const bf16x8*)(tp + k0);
        bf16x8 b0 = *(const bf16x8*)(wp0 + k0);
        bf16x8 b1 = *(const bf16x8*)(wp1 + k0);
        bf16x8 b2 = *(const bf16x8*)(wp2 + k0);
        bf16x8 b3 = *(const bf16x8*)(wp3 + k0);

        float uu[8] = {u0.x, u0.y, u0.z, u0.w, u1.x, u1.y, u1.z, u1.w};
        bf16x8 a;
#pragma unroll
        for (int j = 0; j < 8; ++j)
            a[j] = f2bf((bf2f(h[j]) + bf2f(tv[j])) * uu[j]);

        acc[0] = __builtin_amdgcn_mfma_f32_16x16x32_bf16(a, b0, acc[0], 0, 0, 0);
        acc[1] = __builtin_amdgcn_mfma_f32_16x16x32_bf16(a, b1, acc[1], 0, 0, 0);
        acc[2] = __builtin_amdgcn_mfma_f32_16x16x32_bf16(a, b2, acc[2], 0, 0, 0);
        acc[3] = __builtin_amdgcn_mfma_f32_16x16x32_bf16(a, b3, acc[3], 0, 0, 0);
    }

    const int ql = lane >> 4;
#pragma unroll
    for (int reg = 0; reg < 4; ++reg) {
        int rr = r0 + (wave << 4) + (ql << 2) + reg;
        int q0 = pair_idx[2 * rr];
        int q1 = pair_idx[2 * rr + 1];
        int code = obj_preds[q0] * 151 + obj_preds[q1];
        const float* fr = freq + (size_t)code * 51;
#pragma unroll
        for (int nb = 0; nb < 4; ++nb) {
            int c = (nb << 4) + ml;
            if (c < 51) {
                out[(size_t)rr * 51 + c] = acc[nb][reg] + bctx[c] + fr[c];
            }
        }
    }
}

// ---------------------------------------------------------------------------
extern "C" void kernel_launch(void* const* d_in, const int* in_sizes, int n_in,
                              void* d_out, int out_size, void* d_ws, size_t ws_size,
                              hipStream_t stream)
{
    (void)in_sizes; (void)n_in; (void)out_size; (void)ws_size;

    const float* edge_ctx = (const float*)d_in[0];   // 1280 x 512
    const float* unionf   = (const float*)d_in[1];   // 32768 x 4096
    const float* w_emb    = (const float*)d_in[2];   // 512 x 1024
    const float* b_emb    = (const float*)d_in[3];   // 1024
    const float* w_cat    = (const float*)d_in[4];   // 1024 x 4096
    const float* b_cat    = (const float*)d_in[5];   // 4096
    const float* w_ctx    = (const float*)d_in[6];   // 4096 x 51
    const float* b_ctx    = (const float*)d_in[7];   // 51
    const float* freq     = (const float*)d_in[8];   // 22801 x 51
    const int*   obj_pred = (const int*)d_in[9];     // 1280
    const int*   pair_idx = (const int*)d_in[10];    // 32768 x 2
    float* out = (float*)d_out;                      // 32768 x 51

    char* ws = (char*)d_ws;
    short* WembT    = (short*)(ws);                     // 1024 x 512  bf16 (1 MiB)
    short* WcatT    = (short*)(ws + (1ull  << 20));     // 4096 x 1024 bf16 (8 MiB)
    short* Wt       = (short*)(ws + (9ull  << 20));     // 64 x 4096   bf16 (0.5 MiB)
    short* edge_rep = (short*)(ws + (10ull << 20));     // 1280 x 1024 bf16 (2.5 MiB)
    short* Hbuf     = (short*)(ws + (13ull << 20));     // 1280 x 4096 bf16 (10 MiB)
    short* Tbuf     = (short*)(ws + (23ull << 20));     // 1280 x 4096 bf16 (10 MiB)

    // 1-3: weight transpose + f32->bf16 convert
    transpose_cvt<<<dim3(8, 16),  256, 0, stream>>>(w_emb, WembT, 512, 1024, 1024);
    transpose_cvt<<<dim3(16, 64), 256, 0, stream>>>(w_cat, WcatT, 1024, 4096, 4096);
    transpose_cvt<<<dim3(64, 1),  256, 0, stream>>>(w_ctx, Wt, 4096, 51, 64);

    // 4: edge_rep = relu(edge_ctx @ w_post_emb + b_post_emb)   (1280 x 1024)
    gemm_bt<1><<<dim3(20, 16), 256, 0, stream>>>(edge_ctx, 512, WembT, 512,
                                                 b_emb, edge_rep, 1024, 512, 1);

    // 5: H = edge_rep[:, :512] @ w_post_cat[:512, :] + b_cat   (1280 x 4096)
    //    (b_cat folded in here so fused_rel's hot loop skips it)
    gemm_bt<0><<<dim3(20, 64), 256, 0, stream>>>(edge_rep, 1024, WcatT, 1024,
                                                 b_cat, Hbuf, 4096, 512, 0);
    // 6: T = edge_rep[:, 512:] @ w_post_cat[512:, :]           (1280 x 4096)
    gemm_bt<0><<<dim3(20, 64), 256, 0, stream>>>(edge_rep + 512, 1024, WcatT + 512, 1024,
                                                 nullptr, Tbuf, 4096, 512, 0);

    // 7: fused (H[p0]+T[p1])*union @ w_ctx + b_ctx + freq  -> out (f32)
    fused_rel<<<dim3(512), 256, 0, stream>>>(unionf, Hbuf, Tbuf, Wt, b_ctx,
                                             freq, obj_pred, pair_idx, out);
}

// Round 3
// 830.464 us; speedup vs baseline: 1.1614x; 1.1614x over previous
//
#include <hip/hip_runtime.h>

typedef __attribute__((ext_vector_type(8))) short bf16x8;
typedef __attribute__((ext_vector_type(4))) float f32x4;

__device__ __forceinline__ float bf2f(short s) {
    union { unsigned int i; float f; } v;
    v.i = ((unsigned int)(unsigned short)s) << 16;
    return v.f;
}
__device__ __forceinline__ short f2bf(float f) {
    unsigned int x = __float_as_uint(f);
    unsigned int r = (x + 0x7fffu + ((x >> 16) & 1u)) >> 16;
    return (short)r;
}

// ---------------------------------------------------------------------------
// Transpose f32 -> bf16 with zero-pad of output rows:
// in: R x C (row-major f32) -> out: Cout x R bf16, out[c][r] = (c<C)? in[r][c] : 0
// grid = (R/64, Cout/64), block = 256
// ---------------------------------------------------------------------------
__global__ __launch_bounds__(256) void transpose_cvt(
    const float* __restrict__ in, short* __restrict__ out,
    int R, int C, int Cout)
{
    __shared__ short tile[64][65];
    const int r0 = blockIdx.x << 6;
    const int c0 = blockIdx.y << 6;
    const int t = threadIdx.x;
#pragma unroll
    for (int i = 0; i < 16; ++i) {
        int idx = t + (i << 8);
        int rr = idx >> 6, cc = idx & 63;
        int c = c0 + cc;
        tile[rr][cc] = (c < C) ? f2bf(in[(size_t)(r0 + rr) * C + c]) : (short)0;
    }
    __syncthreads();
#pragma unroll
    for (int i = 0; i < 16; ++i) {
        int idx = t + (i << 8);
        int cc = idx >> 6, rr = idx & 63;
        out[(size_t)(c0 + cc) * R + r0 + rr] = tile[rr][cc];
    }
}

// ---------------------------------------------------------------------------
// C[M,N] = act(A[M,K] @ Bt[N,K]^T + bias[N]), fp32 accumulate, bf16 out.
// Staged LDS, ping-pong double buffer, ONE barrier per K-step (T3 minimum
// 2-phase). XOR-swizzled [64][64] tiles (granule ^= row&7) -> conflict-free
// ds_read_b128 / ds_write_b128 (T2).
// Tile 64x64, BK=64, block=256 (4 waves; wave w -> rows 16w..16w+15).
// grid = (M/64, N/64).
// ---------------------------------------------------------------------------
template<int A_F32>
__global__ __launch_bounds__(256) void gemm_bt(
    const void* __restrict__ Ap, int lda,
    const short* __restrict__ Bt, int ldb,
    const float* __restrict__ bias,      // may be null (f32)
    short* __restrict__ C, int ldc,
    int K, int relu)
{
    __shared__ short As[2][64][64];
    __shared__ short Bs[2][64][64];
    const int t = threadIdx.x;
    const int wave = t >> 6;
    const int lane = t & 63;
    const int ml = lane & 15;
    const int kq = (lane >> 4) << 3;
    const int m0 = blockIdx.x << 6;
    const int n0 = blockIdx.y << 6;

    // staging: thread t covers row rr = t>>2, 16 elements at kc = (t&3)*16
    const int rr = t >> 2;
    const int kc = (t & 3) << 4;
    const int wg0 = (((kc >> 3) ^ (rr & 7)) << 3);       // swizzled write cols
    const int wg1 = ((((kc >> 3) + 1) ^ (rr & 7)) << 3);

    const float* apf = (const float*)Ap + (size_t)(m0 + rr) * lda + kc;
    const short* aps = (const short*)Ap + (size_t)(m0 + rr) * lda + kc;
    const short* bp  = Bt + (size_t)(n0 + rr) * ldb + kc;

    const int x7 = ml & 7;                 // read-side swizzle (all rows %16)
    const int arow = (wave << 4) + ml;

    f32x4 acc[4];
#pragma unroll
    for (int i = 0; i < 4; ++i) acc[i] = (f32x4){0.f, 0.f, 0.f, 0.f};

    float4 x0, x1, x2, x3;
    bf16x8 a0s, a1s, b0s, b1s;
    if (A_F32) {
        x0 = *(const float4*)(apf);     x1 = *(const float4*)(apf + 4);
        x2 = *(const float4*)(apf + 8); x3 = *(const float4*)(apf + 12);
    } else {
        a0s = *(const bf16x8*)(aps);
        a1s = *(const bf16x8*)(aps + 8);
    }
    b0s = *(const bf16x8*)(bp);
    b1s = *(const bf16x8*)(bp + 8);

    const int NS = K >> 6;
    for (int s = 0; s < NS; ++s) {
        const int cur = s & 1;
        bf16x8 a0, a1;
        if (A_F32) {
            a0[0] = f2bf(x0.x); a0[1] = f2bf(x0.y); a0[2] = f2bf(x0.z); a0[3] = f2bf(x0.w);
            a0[4] = f2bf(x1.x); a0[5] = f2bf(x1.y); a0[6] = f2bf(x1.z); a0[7] = f2bf(x1.w);
            a1[0] = f2bf(x2.x); a1[1] = f2bf(x2.y); a1[2] = f2bf(x2.z); a1[3] = f2bf(x2.w);
            a1[4] = f2bf(x3.x); a1[5] = f2bf(x3.y); a1[6] = f2bf(x3.z); a1[7] = f2bf(x3.w);
        } else {
            a0 = a0s; a1 = a1s;
        }
        *(bf16x8*)&As[cur][rr][wg0] = a0;
        *(bf16x8*)&As[cur][rr][wg1] = a1;
        *(bf16x8*)&Bs[cur][rr][wg0] = b0s;
        *(bf16x8*)&Bs[cur][rr][wg1] = b1s;
        __syncthreads();
        if (s + 1 < NS) {                 // prefetch next step during MFMA
            const int k0 = (s + 1) << 6;
            if (A_F32) {
                x0 = *(const float4*)(apf + k0);     x1 = *(const float4*)(apf + k0 + 4);
                x2 = *(const float4*)(apf + k0 + 8); x3 = *(const float4*)(apf + k0 + 12);
            } else {
                a0s = *(const bf16x8*)(aps + k0);
                a1s = *(const bf16x8*)(aps + k0 + 8);
            }
            b0s = *(const bf16x8*)(bp + k0);
            b1s = *(const bf16x8*)(bp + k0 + 8);
        }
#pragma unroll
        for (int ks = 0; ks < 64; ks += 32) {
            const int gb = (ks + kq) >> 3;
            bf16x8 af = *(const bf16x8*)&As[cur][arow][((gb ^ x7) << 3)];
#pragma unroll
            for (int nb = 0; nb < 4; ++nb) {
                bf16x8 bfr = *(const bf16x8*)&Bs[cur][(nb << 4) + ml][((gb ^ x7) << 3)];
                acc[nb] = __builtin_amdgcn_mfma_f32_16x16x32_bf16(af, bfr, acc[nb], 0, 0, 0);
            }
        }
    }

    // C/D layout: col = lane&15, row = (lane>>4)*4 + reg
    const int ql = lane >> 4;
#pragma unroll
    for (int reg = 0; reg < 4; ++reg) {
        int r = m0 + (wave << 4) + (ql << 2) + reg;
#pragma unroll
        for (int nb = 0; nb < 4; ++nb) {
            int c = n0 + (nb << 4) + ml;
            float v = acc[nb][reg];
            if (bias) v += bias[c];
            if (relu) v = fmaxf(v, 0.f);
            C[(size_t)r * ldc + c] = f2bf(v);
        }
    }
}

// ---------------------------------------------------------------------------
// Fused final stage, same 2-phase ping-pong + swizzle template.
// Hm already includes +b_cat (folded in via gemm bias).
//   A'[r,k] = bf16( (Hm[p0[r],k] + Tm[p1[r],k]) * U[r,k] )
//   acc = A' @ Wt^T  (Wt = zero-padded w_ctx^T, 64 x 4096 bf16)
//   out[r,c] = acc + b_ctx[c] + freq[obj[p0]*151+obj[p1], c]   (c < 51, f32)
// grid = 512, block = 256.
// ---------------------------------------------------------------------------
__global__ __launch_bounds__(256) void fused_rel(
    const float* __restrict__ U,        // 32768 x 4096 f32
    const short* __restrict__ Hm,       // 1280 x 4096 bf16 (incl. b_cat)
    const short* __restrict__ Tm,       // 1280 x 4096 bf16
    const short* __restrict__ Wt,       // 64 x 4096 bf16
    const float* __restrict__ bctx,     // 51 f32
    const float* __restrict__ freq,     // 22801 x 51 f32
    const int* __restrict__ obj_preds,  // 1280 int32
    const int* __restrict__ pair_idx,   // 32768 x 2 int32
    float* __restrict__ out)            // 32768 x 51 f32
{
    __shared__ short As[2][64][64];
    __shared__ short Bs[2][64][64];
    const int t = threadIdx.x;
    const int wave = t >> 6;
    const int lane = t & 63;
    const int ml = lane & 15;
    const int kq = (lane >> 4) << 3;
    const int r0 = blockIdx.x << 6;

    const int rr = t >> 2;
    const int kc = (t & 3) << 4;
    const int wg0 = (((kc >> 3) ^ (rr & 7)) << 3);
    const int wg1 = ((((kc >> 3) + 1) ^ (rr & 7)) << 3);

    const int r = r0 + rr;
    const int p0 = pair_idx[2 * r];
    const int p1 = pair_idx[2 * r + 1];

    const float* up = U + (size_t)r * 4096 + kc;
    const short* hp = Hm + (size_t)p0 * 4096 + kc;
    const short* tp = Tm + (size_t)p1 * 4096 + kc;
    const short* wp = Wt + (size_t)rr * 4096 + kc;

    const int x7 = ml & 7;
    const int arow = (wave << 4) + ml;

    f32x4 acc[4];
#pragma unroll
    for (int i = 0; i < 4; ++i) acc[i] = (f32x4){0.f, 0.f, 0.f, 0.f};

    float4 u0, u1, u2, u3;
    bf16x8 h0, h1, t0, t1, w0, w1;
#define LOADG(K0)                                            \
    u0 = *(const float4*)(up + (K0));                        \
    u1 = *(const float4*)(up + (K0) + 4);                    \
    u2 = *(const float4*)(up + (K0) + 8);                    \
    u3 = *(const float4*)(up + (K0) + 12);                   \
    h0 = *(const bf16x8*)(hp + (K0));                        \
    h1 = *(const bf16x8*)(hp + (K0) + 8);                    \
    t0 = *(const bf16x8*)(tp + (K0));                        \
    t1 = *(const bf16x8*)(tp + (K0) + 8);                    \
    w0 = *(const bf16x8*)(wp + (K0));                        \
    w1 = *(const bf16x8*)(wp + (K0) + 8)

    LOADG(0);

    for (int s = 0; s < 64; ++s) {
        const int cur = s & 1;
        float uu[16] = {u0.x, u0.y, u0.z, u0.w, u1.x, u1.y, u1.z, u1.w,
                        u2.x, u2.y, u2.z, u2.w, u3.x, u3.y, u3.z, u3.w};
        bf16x8 a0, a1;
#pragma unroll
        for (int j = 0; j < 8; ++j) {
            a0[j] = f2bf((bf2f(h0[j]) + bf2f(t0[j])) * uu[j]);
            a1[j] = f2bf((bf2f(h1[j]) + bf2f(t1[j])) * uu[8 + j]);
        }
        *(bf16x8*)&As[cur][rr][wg0] = a0;
        *(bf16x8*)&As[cur][rr][wg1] = a1;
        *(bf16x8*)&Bs[cur][rr][wg0] = w0;
        *(bf16x8*)&Bs[cur][rr][wg1] = w1;
        __syncthreads();
        if (s + 1 < 64) {                 // prefetch next step during MFMA
            const int k0 = (s + 1) << 6;
            LOADG(k0);
        }
#pragma unroll
        for (int ks = 0; ks < 64; ks += 32) {
            const int gb = (ks + kq) >> 3;
            bf16x8 af = *(const bf16x8*)&As[cur][arow][((gb ^ x7) << 3)];
#pragma unroll
            for (int nb = 0; nb < 4; ++nb) {
                bf16x8 bfr = *(const bf16x8*)&Bs[cur][(nb << 4) + ml][((gb ^ x7) << 3)];
                acc[nb] = __builtin_amdgcn_mfma_f32_16x16x32_bf16(af, bfr, acc[nb], 0, 0, 0);
            }
        }
    }
#undef LOADG

    const int ql = lane >> 4;
#pragma unroll
    for (int reg = 0; reg < 4; ++reg) {
        int rm = r0 + (wave << 4) + (ql << 2) + reg;
        int q0 = pair_idx[2 * rm];
        int q1 = pair_idx[2 * rm + 1];
        int code = obj_preds[q0] * 151 + obj_preds[q1];
        const float* fr = freq + (size_t)code * 51;
#pragma unroll
        for (int nb = 0; nb < 4; ++nb) {
            int c = (nb << 4) + ml;
            if (c < 51) {
                out[(size_t)rm * 51 + c] = acc[nb][reg] + bctx[c] + fr[c];
            }
        }
    }
}

// ---------------------------------------------------------------------------
extern "C" void kernel_launch(void* const* d_in, const int* in_sizes, int n_in,
                              void* d_out, int out_size, void* d_ws, size_t ws_size,
                              hipStream_t stream)
{
    (void)in_sizes; (void)n_in; (void)out_size; (void)ws_size;

    const float* edge_ctx = (const float*)d_in[0];   // 1280 x 512
    const float* unionf   = (const float*)d_in[1];   // 32768 x 4096
    const float* w_emb    = (const float*)d_in[2];   // 512 x 1024
    const float* b_emb    = (const float*)d_in[3];   // 1024
    const float* w_cat    = (const float*)d_in[4];   // 1024 x 4096
    const float* b_cat    = (const float*)d_in[5];   // 4096
    const float* w_ctx    = (const float*)d_in[6];   // 4096 x 51
    const float* b_ctx    = (const float*)d_in[7];   // 51
    const float* freq     = (const float*)d_in[8];   // 22801 x 51
    const int*   obj_pred = (const int*)d_in[9];     // 1280
    const int*   pair_idx = (const int*)d_in[10];    // 32768 x 2
    float* out = (float*)d_out;                      // 32768 x 51

    char* ws = (char*)d_ws;
    short* WembT    = (short*)(ws);                     // 1024 x 512  bf16 (1 MiB)
    short* WcatT    = (short*)(ws + (1ull  << 20));     // 4096 x 1024 bf16 (8 MiB)
    short* Wt       = (short*)(ws + (9ull  << 20));     // 64 x 4096   bf16 (0.5 MiB)
    short* edge_rep = (short*)(ws + (10ull << 20));     // 1280 x 1024 bf16 (2.5 MiB)
    short* Hbuf     = (short*)(ws + (13ull << 20));     // 1280 x 4096 bf16 (10 MiB)
    short* Tbuf     = (short*)(ws + (23ull << 20));     // 1280 x 4096 bf16 (10 MiB)

    // 1-3: weight transpose + f32->bf16 convert
    transpose_cvt<<<dim3(8, 16),  256, 0, stream>>>(w_emb, WembT, 512, 1024, 1024);
    transpose_cvt<<<dim3(16, 64), 256, 0, stream>>>(w_cat, WcatT, 1024, 4096, 4096);
    transpose_cvt<<<dim3(64, 1),  256, 0, stream>>>(w_ctx, Wt, 4096, 51, 64);

    // 4: edge_rep = relu(edge_ctx @ w_post_emb + b_post_emb)   (1280 x 1024)
    gemm_bt<1><<<dim3(20, 16), 256, 0, stream>>>(edge_ctx, 512, WembT, 512,
                                                 b_emb, edge_rep, 1024, 512, 1);

    // 5: H = edge_rep[:, :512] @ w_post_cat[:512, :] + b_cat   (1280 x 4096)
    //    (b_cat folded in here so fused_rel's hot loop skips it)
    gemm_bt<0><<<dim3(20, 64), 256, 0, stream>>>(edge_rep, 1024, WcatT, 1024,
                                                 b_cat, Hbuf, 4096, 512, 0);
    // 6: T = edge_rep[:, 512:] @ w_post_cat[512:, :]           (1280 x 4096)
    gemm_bt<0><<<dim3(20, 64), 256, 0, stream>>>(edge_rep + 512, 1024, WcatT + 512, 1024,
                                                 nullptr, Tbuf, 4096, 512, 0);

    // 7: fused (H[p0]+T[p1])*union @ w_ctx + b_ctx + freq  -> out (f32)
    fused_rel<<<dim3(512), 256, 0, stream>>>(unionf, Hbuf, Tbuf, Wt, b_ctx,
                                             freq, obj_pred, pair_idx, out);
}

// Round 4
// 830.217 us; speedup vs baseline: 1.1617x; 1.0003x over previous
//
#include <hip/hip_runtime.h>

typedef __attribute__((ext_vector_type(8))) short bf16x8;
typedef __attribute__((ext_vector_type(4))) float f32x4;

__device__ __forceinline__ float bf2f(short s) {
    union { unsigned int i; float f; } v;
    v.i = ((unsigned int)(unsigned short)s) << 16;
    return v.f;
}
__device__ __forceinline__ short f2bf(float f) {
    unsigned int x = __float_as_uint(f);
    unsigned int r = (x + 0x7fffu + ((x >> 16) & 1u)) >> 16;
    return (short)r;
}

// ---------------------------------------------------------------------------
// Transpose f32 -> bf16 with zero-pad of output rows:
// in: R x C (row-major f32) -> out: Cout x R bf16, out[c][r] = (c<C)? in[r][c] : 0
// grid = (R/64, Cout/64), block = 256
// ---------------------------------------------------------------------------
__global__ __launch_bounds__(256) void transpose_cvt(
    const float* __restrict__ in, short* __restrict__ out,
    int R, int C, int Cout)
{
    __shared__ short tile[64][65];
    const int r0 = blockIdx.x << 6;
    const int c0 = blockIdx.y << 6;
    const int t = threadIdx.x;
#pragma unroll
    for (int i = 0; i < 16; ++i) {
        int idx = t + (i << 8);
        int rr = idx >> 6, cc = idx & 63;
        int c = c0 + cc;
        tile[rr][cc] = (c < C) ? f2bf(in[(size_t)(r0 + rr) * C + c]) : (short)0;
    }
    __syncthreads();
#pragma unroll
    for (int i = 0; i < 16; ++i) {
        int idx = t + (i << 8);
        int cc = idx >> 6, rr = idx & 63;
        out[(size_t)(c0 + cc) * R + r0 + rr] = tile[rr][cc];
    }
}

// ---------------------------------------------------------------------------
// C[M,N] = act(A[M,K] @ Bt[N,K]^T + bias[N]), fp32 accumulate, bf16 out.
// Staged LDS, ping-pong double buffer, ONE barrier per K-step, XOR-swizzled
// [64][64] tiles (conflict-free ds_read/write_b128).
// Tile 64x64, BK=64, block=256 (4 waves). grid = (M/64, N/64).
// ---------------------------------------------------------------------------
template<int A_F32>
__global__ __launch_bounds__(256) void gemm_bt(
    const void* __restrict__ Ap, int lda,
    const short* __restrict__ Bt, int ldb,
    const float* __restrict__ bias,      // may be null (f32)
    short* __restrict__ C, int ldc,
    int K, int relu)
{
    __shared__ short As[2][64][64];
    __shared__ short Bs[2][64][64];
    const int t = threadIdx.x;
    const int wave = t >> 6;
    const int lane = t & 63;
    const int ml = lane & 15;
    const int kq = (lane >> 4) << 3;
    const int m0 = blockIdx.x << 6;
    const int n0 = blockIdx.y << 6;

    const int rr = t >> 2;
    const int kc = (t & 3) << 4;
    const int wg0 = (((kc >> 3) ^ (rr & 7)) << 3);       // swizzled write cols
    const int wg1 = ((((kc >> 3) + 1) ^ (rr & 7)) << 3);

    const float* apf = (const float*)Ap + (size_t)(m0 + rr) * lda + kc;
    const short* aps = (const short*)Ap + (size_t)(m0 + rr) * lda + kc;
    const short* bp  = Bt + (size_t)(n0 + rr) * ldb + kc;

    const int x7 = ml & 7;                 // read-side swizzle
    const int arow = (wave << 4) + ml;

    f32x4 acc[4];
#pragma unroll
    for (int i = 0; i < 4; ++i) acc[i] = (f32x4){0.f, 0.f, 0.f, 0.f};

    float4 x0, x1, x2, x3;
    bf16x8 a0s, a1s, b0s, b1s;
    if (A_F32) {
        x0 = *(const float4*)(apf);     x1 = *(const float4*)(apf + 4);
        x2 = *(const float4*)(apf + 8); x3 = *(const float4*)(apf + 12);
    } else {
        a0s = *(const bf16x8*)(aps);
        a1s = *(const bf16x8*)(aps + 8);
    }
    b0s = *(const bf16x8*)(bp);
    b1s = *(const bf16x8*)(bp + 8);

    const int NS = K >> 6;
    for (int s = 0; s < NS; ++s) {
        const int cur = s & 1;
        bf16x8 a0, a1;
        if (A_F32) {
            a0[0] = f2bf(x0.x); a0[1] = f2bf(x0.y); a0[2] = f2bf(x0.z); a0[3] = f2bf(x0.w);
            a0[4] = f2bf(x1.x); a0[5] = f2bf(x1.y); a0[6] = f2bf(x1.z); a0[7] = f2bf(x1.w);
            a1[0] = f2bf(x2.x); a1[1] = f2bf(x2.y); a1[2] = f2bf(x2.z); a1[3] = f2bf(x2.w);
            a1[4] = f2bf(x3.x); a1[5] = f2bf(x3.y); a1[6] = f2bf(x3.z); a1[7] = f2bf(x3.w);
        } else {
            a0 = a0s; a1 = a1s;
        }
        *(bf16x8*)&As[cur][rr][wg0] = a0;
        *(bf16x8*)&As[cur][rr][wg1] = a1;
        *(bf16x8*)&Bs[cur][rr][wg0] = b0s;
        *(bf16x8*)&Bs[cur][rr][wg1] = b1s;
        __syncthreads();
        if (s + 1 < NS) {                 // prefetch next step during MFMA
            const int k0 = (s + 1) << 6;
            if (A_F32) {
                x0 = *(const float4*)(apf + k0);     x1 = *(const float4*)(apf + k0 + 4);
                x2 = *(const float4*)(apf + k0 + 8); x3 = *(const float4*)(apf + k0 + 12);
            } else {
                a0s = *(const bf16x8*)(aps + k0);
                a1s = *(const bf16x8*)(aps + k0 + 8);
            }
            b0s = *(const bf16x8*)(bp + k0);
            b1s = *(const bf16x8*)(bp + k0 + 8);
        }
#pragma unroll
        for (int ks = 0; ks < 64; ks += 32) {
            const int gb = (ks + kq) >> 3;
            bf16x8 af = *(const bf16x8*)&As[cur][arow][((gb ^ x7) << 3)];
#pragma unroll
            for (int nb = 0; nb < 4; ++nb) {
                bf16x8 bfr = *(const bf16x8*)&Bs[cur][(nb << 4) + ml][((gb ^ x7) << 3)];
                acc[nb] = __builtin_amdgcn_mfma_f32_16x16x32_bf16(af, bfr, acc[nb], 0, 0, 0);
            }
        }
    }

    // C/D layout: col = lane&15, row = (lane>>4)*4 + reg
    const int ql = lane >> 4;
#pragma unroll
    for (int reg = 0; reg < 4; ++reg) {
        int r = m0 + (wave << 4) + (ql << 2) + reg;
#pragma unroll
        for (int nb = 0; nb < 4; ++nb) {
            int c = n0 + (nb << 4) + ml;
            float v = acc[nb][reg];
            if (bias) v += bias[c];
            if (relu) v = fmaxf(v, 0.f);
            C[(size_t)r * ldc + c] = f2bf(v);
        }
    }
}

// ---------------------------------------------------------------------------
// Fused stage, K-SPLIT x2 for occupancy (grid 512 x 2 = 4 blocks/CU).
// Block (bx, z) computes partial acc over K in [z*2048, z*2048+2048) and
// writes f32 partials to P[z][32768][64]. bctx/freq folded in reduce_out.
// Same 2-phase ping-pong + swizzle template as gemm_bt.
// ---------------------------------------------------------------------------
__global__ __launch_bounds__(256) void fused_rel(
    const float* __restrict__ U,        // 32768 x 4096 f32
    const short* __restrict__ Hm,       // 1280 x 4096 bf16 (incl. b_cat)
    const short* __restrict__ Tm,       // 1280 x 4096 bf16
    const short* __restrict__ Wt,       // 64 x 4096 bf16
    const int* __restrict__ pair_idx,   // 32768 x 2 int32
    float* __restrict__ P)              // 2 x 32768 x 64 f32 partials
{
    __shared__ short As[2][64][64];
    __shared__ short Bs[2][64][64];
    const int t = threadIdx.x;
    const int wave = t >> 6;
    const int lane = t & 63;
    const int ml = lane & 15;
    const int kq = (lane >> 4) << 3;
    const int r0 = blockIdx.x << 6;
    const int kbase = blockIdx.y << 11;     // 0 or 2048

    const int rr = t >> 2;
    const int kc = (t & 3) << 4;
    const int wg0 = (((kc >> 3) ^ (rr & 7)) << 3);
    const int wg1 = ((((kc >> 3) + 1) ^ (rr & 7)) << 3);

    const int r = r0 + rr;
    const int p0 = pair_idx[2 * r];
    const int p1 = pair_idx[2 * r + 1];

    const float* up = U  + (size_t)r  * 4096 + kbase + kc;
    const short* hp = Hm + (size_t)p0 * 4096 + kbase + kc;
    const short* tp = Tm + (size_t)p1 * 4096 + kbase + kc;
    const short* wp = Wt + (size_t)rr * 4096 + kbase + kc;

    const int x7 = ml & 7;
    const int arow = (wave << 4) + ml;

    f32x4 acc[4];
#pragma unroll
    for (int i = 0; i < 4; ++i) acc[i] = (f32x4){0.f, 0.f, 0.f, 0.f};

    float4 u0, u1, u2, u3;
    bf16x8 h0, h1, t0, t1, w0, w1;
#define LOADG(K0)                                            \
    u0 = *(const float4*)(up + (K0));                        \
    u1 = *(const float4*)(up + (K0) + 4);                    \
    u2 = *(const float4*)(up + (K0) + 8);                    \
    u3 = *(const float4*)(up + (K0) + 12);                   \
    h0 = *(const bf16x8*)(hp + (K0));                        \
    h1 = *(const bf16x8*)(hp + (K0) + 8);                    \
    t0 = *(const bf16x8*)(tp + (K0));                        \
    t1 = *(const bf16x8*)(tp + (K0) + 8);                    \
    w0 = *(const bf16x8*)(wp + (K0));                        \
    w1 = *(const bf16x8*)(wp + (K0) + 8)

    LOADG(0);

    for (int s = 0; s < 32; ++s) {
        const int cur = s & 1;
        float uu[16] = {u0.x, u0.y, u0.z, u0.w, u1.x, u1.y, u1.z, u1.w,
                        u2.x, u2.y, u2.z, u2.w, u3.x, u3.y, u3.z, u3.w};
        bf16x8 a0, a1;
#pragma unroll
        for (int j = 0; j < 8; ++j) {
            a0[j] = f2bf((bf2f(h0[j]) + bf2f(t0[j])) * uu[j]);
            a1[j] = f2bf((bf2f(h1[j]) + bf2f(t1[j])) * uu[8 + j]);
        }
        *(bf16x8*)&As[cur][rr][wg0] = a0;
        *(bf16x8*)&As[cur][rr][wg1] = a1;
        *(bf16x8*)&Bs[cur][rr][wg0] = w0;
        *(bf16x8*)&Bs[cur][rr][wg1] = w1;
        __syncthreads();
        if (s + 1 < 32) {                 // prefetch next step during MFMA
            const int k0 = (s + 1) << 6;
            LOADG(k0);
        }
#pragma unroll
        for (int ks = 0; ks < 64; ks += 32) {
            const int gb = (ks + kq) >> 3;
            bf16x8 af = *(const bf16x8*)&As[cur][arow][((gb ^ x7) << 3)];
#pragma unroll
            for (int nb = 0; nb < 4; ++nb) {
                bf16x8 bfr = *(const bf16x8*)&Bs[cur][(nb << 4) + ml][((gb ^ x7) << 3)];
                acc[nb] = __builtin_amdgcn_mfma_f32_16x16x32_bf16(af, bfr, acc[nb], 0, 0, 0);
            }
        }
    }
#undef LOADG

    float* Pz = P + ((size_t)blockIdx.y << 21);   // 32768*64 per split
    const int ql = lane >> 4;
#pragma unroll
    for (int reg = 0; reg < 4; ++reg) {
        int rm = r0 + (wave << 4) + (ql << 2) + reg;
#pragma unroll
        for (int nb = 0; nb < 4; ++nb) {
            int c = (nb << 4) + ml;
            Pz[((size_t)rm << 6) + c] = acc[nb][reg];
        }
    }
}

// ---------------------------------------------------------------------------
// out[r,c] = P[0][r,c] + P[1][r,c] + bctx[c] + freq[code(r), c]   (c < 51)
// grid = 8192, block = 256  (one thread per (r, c) with c in [0,64))
// ---------------------------------------------------------------------------
__global__ __launch_bounds__(256) void reduce_out(
    const float* __restrict__ P,        // 2 x 32768 x 64 f32
    const float* __restrict__ bctx,     // 51 f32
    const float* __restrict__ freq,     // 22801 x 51 f32
    const int* __restrict__ obj_preds,  // 1280 int32
    const int* __restrict__ pair_idx,   // 32768 x 2 int32
    float* __restrict__ out)            // 32768 x 51 f32
{
    const int idx = blockIdx.x * 256 + threadIdx.x;   // 0 .. 32768*64-1
    const int r = idx >> 6;
    const int c = idx & 63;
    if (c < 51) {
        int p0 = pair_idx[2 * r];
        int p1 = pair_idx[2 * r + 1];
        int code = obj_preds[p0] * 151 + obj_preds[p1];
        out[(size_t)r * 51 + c] = P[idx] + P[(1u << 21) + idx]
                                + bctx[c] + freq[(size_t)code * 51 + c];
    }
}

// ---------------------------------------------------------------------------
extern "C" void kernel_launch(void* const* d_in, const int* in_sizes, int n_in,
                              void* d_out, int out_size, void* d_ws, size_t ws_size,
                              hipStream_t stream)
{
    (void)in_sizes; (void)n_in; (void)out_size; (void)ws_size;

    const float* edge_ctx = (const float*)d_in[0];   // 1280 x 512
    const float* unionf   = (const float*)d_in[1];   // 32768 x 4096
    const float* w_emb    = (const float*)d_in[2];   // 512 x 1024
    const float* b_emb    = (const float*)d_in[3];   // 1024
    const float* w_cat    = (const float*)d_in[4];   // 1024 x 4096
    const float* b_cat    = (const float*)d_in[5];   // 4096
    const float* w_ctx    = (const float*)d_in[6];   // 4096 x 51
    const float* b_ctx    = (const float*)d_in[7];   // 51
    const float* freq     = (const float*)d_in[8];   // 22801 x 51
    const int*   obj_pred = (const int*)d_in[9];     // 1280
    const int*   pair_idx = (const int*)d_in[10];    // 32768 x 2
    float* out = (float*)d_out;                      // 32768 x 51

    char* ws = (char*)d_ws;
    short* WembT    = (short*)(ws);                     // 1024 x 512  bf16 (1 MiB)
    short* WcatT    = (short*)(ws + (1ull  << 20));     // 4096 x 1024 bf16 (8 MiB)
    short* Wt       = (short*)(ws + (9ull  << 20));     // 64 x 4096   bf16 (0.5 MiB)
    short* edge_rep = (short*)(ws + (10ull << 20));     // 1280 x 1024 bf16 (2.5 MiB)
    short* Hbuf     = (short*)(ws + (13ull << 20));     // 1280 x 4096 bf16 (10 MiB)
    short* Tbuf     = (short*)(ws + (23ull << 20));     // 1280 x 4096 bf16 (10 MiB)
    float* Pbuf     = (float*)(ws + (33ull << 20));     // 2 x 32768 x 64 f32 (16 MiB)

    // 1-3: weight transpose + f32->bf16 convert
    transpose_cvt<<<dim3(8, 16),  256, 0, stream>>>(w_emb, WembT, 512, 1024, 1024);
    transpose_cvt<<<dim3(16, 64), 256, 0, stream>>>(w_cat, WcatT, 1024, 4096, 4096);
    transpose_cvt<<<dim3(64, 1),  256, 0, stream>>>(w_ctx, Wt, 4096, 51, 64);

    // 4: edge_rep = relu(edge_ctx @ w_post_emb + b_post_emb)   (1280 x 1024)
    gemm_bt<1><<<dim3(20, 16), 256, 0, stream>>>(edge_ctx, 512, WembT, 512,
                                                 b_emb, edge_rep, 1024, 512, 1);

    // 5: H = edge_rep[:, :512] @ w_post_cat[:512, :] + b_cat   (1280 x 4096)
    gemm_bt<0><<<dim3(20, 64), 256, 0, stream>>>(edge_rep, 1024, WcatT, 1024,
                                                 b_cat, Hbuf, 4096, 512, 0);
    // 6: T = edge_rep[:, 512:] @ w_post_cat[512:, :]           (1280 x 4096)
    gemm_bt<0><<<dim3(20, 64), 256, 0, stream>>>(edge_rep + 512, 1024, WcatT + 512, 1024,
                                                 nullptr, Tbuf, 4096, 512, 0);

    // 7: fused (H[p0]+T[p1])*union @ w_ctx -> partials (K-split x2)
    fused_rel<<<dim3(512, 2), 256, 0, stream>>>(unionf, Hbuf, Tbuf, Wt,
                                                pair_idx, Pbuf);

    // 8: out = P0 + P1 + b_ctx + freq
    reduce_out<<<dim3(8192), 256, 0, stream>>>(Pbuf, b_ctx, freq,
                                               obj_pred, pair_idx, out);
}

// Round 6
// 808.049 us; speedup vs baseline: 1.1936x; 1.0274x over previous
//
#include <hip/hip_runtime.h>

typedef __attribute__((ext_vector_type(8))) short bf16x8;
typedef __attribute__((ext_vector_type(4))) float f32x4;

__device__ __forceinline__ float bf2f(short s) {
    union { unsigned int i; float f; } v;
    v.i = ((unsigned int)(unsigned short)s) << 16;
    return v.f;
}
__device__ __forceinline__ short f2bf(float f) {
    unsigned int x = __float_as_uint(f);
    unsigned int r = (x + 0x7fffu + ((x >> 16) & 1u)) >> 16;
    return (short)r;
}

// ---------------------------------------------------------------------------
// All three weight transposes (f32 -> bf16, zero-pad output rows) in ONE
// launch. Flattened grid of 1216 blocks:
//   [0,128)    w_emb  512x1024 -> WembT 1024x512    (8 x 16 tiles)
//   [128,1152) w_cat 1024x4096 -> WcatT 4096x1024   (16 x 64 tiles)
//   [1152,1216) w_ctx 4096x51  -> Wt    64x4096     (64 x 1 tiles)
// block = 256
// ---------------------------------------------------------------------------
__global__ __launch_bounds__(256) void prep_all(
    const float* __restrict__ w_emb, short* __restrict__ WembT,
    const float* __restrict__ w_cat, short* __restrict__ WcatT,
    const float* __restrict__ w_ctx, short* __restrict__ Wt)
{
    __shared__ short tile[64][65];
    const int b = blockIdx.x;
    const float* in; short* out; int R, C, bx, by;
    if (b < 128)        { in = w_emb; out = WembT; R = 512;  C = 1024; bx = b & 7;  by = b >> 3; }
    else if (b < 1152)  { int l = b - 128;  in = w_cat; out = WcatT; R = 1024; C = 4096; bx = l & 15; by = l >> 4; }
    else                { int l = b - 1152; in = w_ctx; out = Wt;    R = 4096; C = 51;   bx = l;      by = 0;      }
    const int r0 = bx << 6;
    const int c0 = by << 6;
    const int t = threadIdx.x;
#pragma unroll
    for (int i = 0; i < 16; ++i) {
        int idx = t + (i << 8);
        int rr = idx >> 6, cc = idx & 63;
        int c = c0 + cc;
        tile[rr][cc] = (c < C) ? f2bf(in[(size_t)(r0 + rr) * C + c]) : (short)0;
    }
    __syncthreads();
#pragma unroll
    for (int i = 0; i < 16; ++i) {
        int idx = t + (i << 8);
        int cc = idx >> 6, rr = idx & 63;
        out[(size_t)(c0 + cc) * R + r0 + rr] = tile[rr][cc];
    }
}

// ---------------------------------------------------------------------------
// Shared GEMM core: C[64,64] tile = act(A @ Bt^T + bias), fp32 acc, bf16 out.
// Staged LDS, ping-pong double buffer, ONE barrier per K-step, XOR-swizzled
// [64][64] tiles (conflict-free ds_read/write_b128). 4 waves / 256 threads.
// ---------------------------------------------------------------------------
template<int A_F32>
__device__ __forceinline__ void gemm_core(
    short (*As)[64][64], short (*Bs)[64][64],
    const void* __restrict__ Ap, int lda,
    const short* __restrict__ Bt, int ldb,
    const float* __restrict__ bias,      // may be null (f32)
    short* __restrict__ C, int ldc,
    int K, int relu, int m0, int n0)
{
    const int t = threadIdx.x;
    const int wave = t >> 6;
    const int lane = t & 63;
    const int ml = lane & 15;
    const int kq = (lane >> 4) << 3;

    const int rr = t >> 2;
    const int kc = (t & 3) << 4;
    const int wg0 = (((kc >> 3) ^ (rr & 7)) << 3);       // swizzled write cols
    const int wg1 = ((((kc >> 3) + 1) ^ (rr & 7)) << 3);

    const float* apf = (const float*)Ap + (size_t)(m0 + rr) * lda + kc;
    const short* aps = (const short*)Ap + (size_t)(m0 + rr) * lda + kc;
    const short* bp  = Bt + (size_t)(n0 + rr) * ldb + kc;

    const int x7 = ml & 7;                 // read-side swizzle
    const int arow = (wave << 4) + ml;

    f32x4 acc[4];
#pragma unroll
    for (int i = 0; i < 4; ++i) acc[i] = (f32x4){0.f, 0.f, 0.f, 0.f};

    float4 x0, x1, x2, x3;
    bf16x8 a0s, a1s, b0s, b1s;
    if (A_F32) {
        x0 = *(const float4*)(apf);     x1 = *(const float4*)(apf + 4);
        x2 = *(const float4*)(apf + 8); x3 = *(const float4*)(apf + 12);
    } else {
        a0s = *(const bf16x8*)(aps);
        a1s = *(const bf16x8*)(aps + 8);
    }
    b0s = *(const bf16x8*)(bp);
    b1s = *(const bf16x8*)(bp + 8);

    const int NS = K >> 6;
    for (int s = 0; s < NS; ++s) {
        const int cur = s & 1;
        bf16x8 a0, a1;
        if (A_F32) {
            a0[0] = f2bf(x0.x); a0[1] = f2bf(x0.y); a0[2] = f2bf(x0.z); a0[3] = f2bf(x0.w);
            a0[4] = f2bf(x1.x); a0[5] = f2bf(x1.y); a0[6] = f2bf(x1.z); a0[7] = f2bf(x1.w);
            a1[0] = f2bf(x2.x); a1[1] = f2bf(x2.y); a1[2] = f2bf(x2.z); a1[3] = f2bf(x2.w);
            a1[4] = f2bf(x3.x); a1[5] = f2bf(x3.y); a1[6] = f2bf(x3.z); a1[7] = f2bf(x3.w);
        } else {
            a0 = a0s; a1 = a1s;
        }
        *(bf16x8*)&(*As)[cur << 6 | rr][wg0] = a0;   // [2][64][64] flattened
        *(bf16x8*)&(*As)[cur << 6 | rr][wg1] = a1;
        *(bf16x8*)&(*Bs)[cur << 6 | rr][wg0] = b0s;
        *(bf16x8*)&(*Bs)[cur << 6 | rr][wg1] = b1s;
        __syncthreads();
        if (s + 1 < NS) {                 // prefetch next step during MFMA
            const int k0 = (s + 1) << 6;
            if (A_F32) {
                x0 = *(const float4*)(apf + k0);     x1 = *(const float4*)(apf + k0 + 4);
                x2 = *(const float4*)(apf + k0 + 8); x3 = *(const float4*)(apf + k0 + 12);
            } else {
                a0s = *(const bf16x8*)(aps + k0);
                a1s = *(const bf16x8*)(aps + k0 + 8);
            }
            b0s = *(const bf16x8*)(bp + k0);
            b1s = *(const bf16x8*)(bp + k0 + 8);
        }
#pragma unroll
        for (int ks = 0; ks < 64; ks += 32) {
            const int gb = (ks + kq) >> 3;
            bf16x8 af = *(const bf16x8*)&(*As)[cur << 6 | arow][((gb ^ x7) << 3)];
#pragma unroll
            for (int nb = 0; nb < 4; ++nb) {
                bf16x8 bfr = *(const bf16x8*)&(*Bs)[cur << 6 | ((nb << 4) + ml)][((gb ^ x7) << 3)];
                acc[nb] = __builtin_amdgcn_mfma_f32_16x16x32_bf16(af, bfr, acc[nb], 0, 0, 0);
            }
        }
    }

    // C/D layout: col = lane&15, row = (lane>>4)*4 + reg
    const int ql = lane >> 4;
#pragma unroll
    for (int reg = 0; reg < 4; ++reg) {
        int r = m0 + (wave << 4) + (ql << 2) + reg;
#pragma unroll
        for (int nb = 0; nb < 4; ++nb) {
            int c = n0 + (nb << 4) + ml;
            float v = acc[nb][reg];
            if (bias) v += bias[c];
            if (relu) v = fmaxf(v, 0.f);
            C[(size_t)r * ldc + c] = f2bf(v);
        }
    }
}

// edge_rep = relu(edge_ctx @ w_post_emb + b_post_emb); A is f32.
__global__ __launch_bounds__(256) void gemm_emb(
    const float* __restrict__ Ap, int lda,
    const short* __restrict__ Bt, int ldb,
    const float* __restrict__ bias,
    short* __restrict__ C, int ldc, int K)
{
    __shared__ short As[128][64];    // [2][64][64]
    __shared__ short Bs[128][64];
    gemm_core<1>((short (*)[64][64])As, (short (*)[64][64])Bs,
                 Ap, lda, Bt, ldb, bias, C, ldc, K, 1,
                 blockIdx.x << 6, blockIdx.y << 6);
}

// H and T GEMMs in one launch: z=0 -> H (bias=b_cat), z=1 -> T (no bias).
__global__ __launch_bounds__(256) void gemm_ht(
    const short* __restrict__ edge_rep,
    const short* __restrict__ WcatT,
    const float* __restrict__ b_cat,
    short* __restrict__ Hbuf, short* __restrict__ Tbuf)
{
    __shared__ short As[128][64];
    __shared__ short Bs[128][64];
    const int z = blockIdx.z;
    gemm_core<0>((short (*)[64][64])As, (short (*)[64][64])Bs,
                 edge_rep + (z ? 512 : 0), 1024,
                 WcatT + (z ? 512 : 0), 1024,
                 z ? (const float*)nullptr : b_cat,
                 z ? Tbuf : Hbuf, 4096, 512, 0,
                 blockIdx.x << 6, blockIdx.y << 6);
}

// ---------------------------------------------------------------------------
// Fused final stage (single K-pass), same 2-phase ping-pong + swizzle.
// Hm already includes +b_cat (folded via gemm bias).
//   A'[r,k] = bf16( (Hm[p0[r],k] + Tm[p1[r],k]) * U[r,k] )
//   acc = A' @ Wt^T  (Wt = zero-padded w_ctx^T, 64 x 4096 bf16)
//   out[r,c] = acc + b_ctx[c] + freq[obj[p0]*151+obj[p1], c]   (c < 51, f32)
// grid = 512, block = 256.
// ---------------------------------------------------------------------------
__global__ __launch_bounds__(256) void fused_rel(
    const float* __restrict__ U,        // 32768 x 4096 f32
    const short* __restrict__ Hm,       // 1280 x 4096 bf16 (incl. b_cat)
    const short* __restrict__ Tm,       // 1280 x 4096 bf16
    const short* __restrict__ Wt,       // 64 x 4096 bf16
    const float* __restrict__ bctx,     // 51 f32
    const float* __restrict__ freq,     // 22801 x 51 f32
    const int* __restrict__ obj_preds,  // 1280 int32
    const int* __restrict__ pair_idx,   // 32768 x 2 int32
    float* __restrict__ out)            // 32768 x 51 f32
{
    __shared__ short As[2][64][64];
    __shared__ short Bs[2][64][64];
    const int t = threadIdx.x;
    const int wave = t >> 6;
    const int lane = t & 63;
    const int ml = lane & 15;
    const int kq = (lane >> 4) << 3;
    const int r0 = blockIdx.x << 6;

    const int rr = t >> 2;
    const int kc = (t & 3) << 4;
    const int wg0 = (((kc >> 3) ^ (rr & 7)) << 3);
    const int wg1 = ((((kc >> 3) + 1) ^ (rr & 7)) << 3);

    const int r = r0 + rr;
    const int p0 = pair_idx[2 * r];
    const int p1 = pair_idx[2 * r + 1];

    const float* up = U + (size_t)r * 4096 + kc;
    const short* hp = Hm + (size_t)p0 * 4096 + kc;
    const short* tp = Tm + (size_t)p1 * 4096 + kc;
    const short* wp = Wt + (size_t)rr * 4096 + kc;

    const int x7 = ml & 7;
    const int arow = (wave << 4) + ml;

    f32x4 acc[4];
#pragma unroll
    for (int i = 0; i < 4; ++i) acc[i] = (f32x4){0.f, 0.f, 0.f, 0.f};

    float4 u0, u1, u2, u3;
    bf16x8 h0, h1, t0, t1, w0, w1;
#define LOADG(K0)                                            \
    u0 = *(const float4*)(up + (K0));                        \
    u1 = *(const float4*)(up + (K0) + 4);                    \
    u2 = *(const float4*)(up + (K0) + 8);                    \
    u3 = *(const float4*)(up + (K0) + 12);                   \
    h0 = *(const bf16x8*)(hp + (K0));                        \
    h1 = *(const bf16x8*)(hp + (K0) + 8);                    \
    t0 = *(const bf16x8*)(tp + (K0));                        \
    t1 = *(const bf16x8*)(tp + (K0) + 8);                    \
    w0 = *(const bf16x8*)(wp + (K0));                        \
    w1 = *(const bf16x8*)(wp + (K0) + 8)

    LOADG(0);

    for (int s = 0; s < 64; ++s) {
        const int cur = s & 1;
        float uu[16] = {u0.x, u0.y, u0.z, u0.w, u1.x, u1.y, u1.z, u1.w,
                        u2.x, u2.y, u2.z, u2.w, u3.x, u3.y, u3.z, u3.w};
        bf16x8 a0, a1;
#pragma unroll
        for (int j = 0; j < 8; ++j) {
            a0[j] = f2bf((bf2f(h0[j]) + bf2f(t0[j])) * uu[j]);
            a1[j] = f2bf((bf2f(h1[j]) + bf2f(t1[j])) * uu[8 + j]);
        }
        *(bf16x8*)&As[cur][rr][wg0] = a0;
        *(bf16x8*)&As[cur][rr][wg1] = a1;
        *(bf16x8*)&Bs[cur][rr][wg0] = w0;
        *(bf16x8*)&Bs[cur][rr][wg1] = w1;
        __syncthreads();
        if (s + 1 < 64) {                 // prefetch next step during MFMA
            const int k0 = (s + 1) << 6;
            LOADG(k0);
        }
#pragma unroll
        for (int ks = 0; ks < 64; ks += 32) {
            const int gb = (ks + kq) >> 3;
            bf16x8 af = *(const bf16x8*)&As[cur][arow][((gb ^ x7) << 3)];
#pragma unroll
            for (int nb = 0; nb < 4; ++nb) {
                bf16x8 bfr = *(const bf16x8*)&Bs[cur][(nb << 4) + ml][((gb ^ x7) << 3)];
                acc[nb] = __builtin_amdgcn_mfma_f32_16x16x32_bf16(af, bfr, acc[nb], 0, 0, 0);
            }
        }
    }
#undef LOADG

    const int ql = lane >> 4;
#pragma unroll
    for (int reg = 0; reg < 4; ++reg) {
        int rm = r0 + (wave << 4) + (ql << 2) + reg;
        int q0 = pair_idx[2 * rm];
        int q1 = pair_idx[2 * rm + 1];
        int code = obj_preds[q0] * 151 + obj_preds[q1];
        const float* fr = freq + (size_t)code * 51;
#pragma unroll
        for (int nb = 0; nb < 4; ++nb) {
            int c = (nb << 4) + ml;
            if (c < 51) {
                out[(size_t)rm * 51 + c] = acc[nb][reg] + bctx[c] + fr[c];
            }
        }
    }
}

// ---------------------------------------------------------------------------
extern "C" void kernel_launch(void* const* d_in, const int* in_sizes, int n_in,
                              void* d_out, int out_size, void* d_ws, size_t ws_size,
                              hipStream_t stream)
{
    (void)in_sizes; (void)n_in; (void)out_size; (void)ws_size;

    const float* edge_ctx = (const float*)d_in[0];   // 1280 x 512
    const float* unionf   = (const float*)d_in[1];   // 32768 x 4096
    const float* w_emb    = (const float*)d_in[2];   // 512 x 1024
    const float* b_emb    = (const float*)d_in[3];   // 1024
    const float* w_cat    = (const float*)d_in[4];   // 1024 x 4096
    const float* b_cat    = (const float*)d_in[5];   // 4096
    const float* w_ctx    = (const float*)d_in[6];   // 4096 x 51
    const float* b_ctx    = (const float*)d_in[7];   // 51
    const float* freq     = (const float*)d_in[8];   // 22801 x 51
    const int*   obj_pred = (const int*)d_in[9];     // 1280
    const int*   pair_idx = (const int*)d_in[10];    // 32768 x 2
    float* out = (float*)d_out;                      // 32768 x 51

    char* ws = (char*)d_ws;
    short* WembT    = (short*)(ws);                     // 1024 x 512  bf16 (1 MiB)
    short* WcatT    = (short*)(ws + (1ull  << 20));     // 4096 x 1024 bf16 (8 MiB)
    short* Wt       = (short*)(ws + (9ull  << 20));     // 64 x 4096   bf16 (0.5 MiB)
    short* edge_rep = (short*)(ws + (10ull << 20));     // 1280 x 1024 bf16 (2.5 MiB)
    short* Hbuf     = (short*)(ws + (13ull << 20));     // 1280 x 4096 bf16 (10 MiB)
    short* Tbuf     = (short*)(ws + (23ull << 20));     // 1280 x 4096 bf16 (10 MiB)

    // 1: all weight transposes (f32 -> bf16) in one launch
    prep_all<<<dim3(1216), 256, 0, stream>>>(w_emb, WembT, w_cat, WcatT, w_ctx, Wt);

    // 2: edge_rep = relu(edge_ctx @ w_post_emb + b_post_emb)   (1280 x 1024)
    gemm_emb<<<dim3(20, 16), 256, 0, stream>>>(edge_ctx, 512, WembT, 512,
                                               b_emb, edge_rep, 1024, 512);

    // 3: H = edge_rep[:, :512] @ w_post_cat[:512, :] + b_cat   (z=0)
    //    T = edge_rep[:, 512:] @ w_post_cat[512:, :]           (z=1)
    gemm_ht<<<dim3(20, 64, 2), 256, 0, stream>>>(edge_rep, WcatT, b_cat, Hbuf, Tbuf);

    // 4: fused (H[p0]+T[p1])*union @ w_ctx + b_ctx + freq -> out (f32)
    fused_rel<<<dim3(512), 256, 0, stream>>>(unionf, Hbuf, Tbuf, Wt, b_ctx,
                                             freq, obj_pred, pair_idx, out);
}